// Round 18
// baseline (168.599 us; speedup 1.0000x reference)
//
#include <hip/hip_runtime.h>
#include <hip/hip_bf16.h>
#include <math.h>

// ---------------------------------------------------------------------------
// Round 25: SYMMETRIC LAYER-SPLIT -- the one untested structural cell.
// All prior structures specialized waves BY LAYER (P=L1+L2 ~170 VALU chain,
// C=L3+L4 ~70); phase = max(P,C) + stall (r12/r18: span transfers 1:1).
// New: split by OUTPUT-FEATURE HALF, symmetric in layers. Wave w holds
// W2-half + W3-half (64+64 = 128 AGPR, SAME total as before) for features
// w*64..w*64+63. Per tile each wave: build 2 Y1 kk-slices (40 VALU) ->
// 16 MFMA L2-half -> Y2-half to LDS; 16 MFMA L3-half on PREVIOUS tile's
// full Y2 -> L4 half-partial. Balanced ~100 VALU + 32 MFMA per wave, and
// each body has TWO independent chains (L2(t), L3(t-1)) the compiler can
// interleave intra-wave. Components all proven: distributed Y1 build/slot
// formulas (r9/r10, verified), Y2 swizzle (r8-r24), vs half-partials +
// single shuffle (r16), bias tables (r13), r22 vectorized prologue.
// Uniform control flow (no role divergence), barriers trivially matched.
// LDS 39.1KB (hshT overlaid on vs pool) keeps 4 blocks/CU.
// Falsifier: WRITE_SIZE >> 64KB = a weight array fell out of AGPRs ->
// revert to r24 (preserved). Numerics: only L4 half-sum reassociation
// (~1e-6, r10-proven); absmax ~0.125 vs thr 0.4725.
// ---------------------------------------------------------------------------

#define B_N    16384
#define KQ     51
#define HD     128
#define IND    64
#define BLK    128               // 2 SYMMETRIC waves
#define RPB    16                // b-rows per block
#define GRID   (B_N / RPB)       // 1024
#define TPB    ((RPB * KQ) / 16) // 51 tiles per block (exact)

typedef __attribute__((ext_vector_type(8))) short short8;
typedef __attribute__((ext_vector_type(4))) float f32x4;

union S8U { short8 s8; unsigned u[4]; };

__device__ __forceinline__ unsigned short f2bf(float f) {
    __hip_bfloat16 t = __float2bfloat16(f);
    return *reinterpret_cast<unsigned short*>(&t);
}

#if defined(__gfx950__) && defined(__has_builtin)
#if __has_builtin(__builtin_amdgcn_cvt_pk_bf16_f32)
#define HAVE_PK_BF16 1
#endif
#endif

__device__ __forceinline__ unsigned pk_bf16(float lo, float hi) {
#ifdef HAVE_PK_BF16
    typedef __attribute__((ext_vector_type(2))) __bf16 bfv2;
    bfv2 r = __builtin_amdgcn_cvt_pk_bf16_f32(lo, hi);
    return *reinterpret_cast<unsigned*>(&r);
#else
    return (unsigned)f2bf(lo) | ((unsigned)f2bf(hi) << 16);
#endif
}

__launch_bounds__(BLK, 2)
__global__ void umnn_fused(const float* __restrict__ x,  const float* __restrict__ h,
                           const float* __restrict__ W1, const float* __restrict__ b1,
                           const float* __restrict__ W2, const float* __restrict__ b2,
                           const float* __restrict__ W3, const float* __restrict__ b3,
                           const float* __restrict__ W4, const float* __restrict__ b4,
                           float* __restrict__ out)
{
    __shared__ __align__(16) float hpL[RPB * HD];      // 8 KB block hpart
    __shared__ __align__(16) char  y1x[2][4096];       // 8 KB Y1 double buffer
    __shared__ __align__(16) char  y2x[2][4096];       // 8 KB Y2 double buffer
    __shared__ __align__(16) float poolF[2 * TPB * 32];// 12.75 KB overlay:
                                                       //   prologue: hshT[63*20]
                                                       //   loop: vs halves (per wave)
    __shared__ __align__(16) float b2f[HD], b3f[HD];   // 1 KB fp32 bias tables
    __shared__ float xL[RPB];
    __shared__ float sSteps[KQ], sCcw[KQ];
    __shared__ float red2[2];

    float* hshT = poolF;                               // prologue-only alias

    const int tid  = threadIdx.x;
    const int w    = tid >> 6;          // symmetric wave 0/1
    const int lane = tid & 63;
    const int q    = lane >> 4;
    const int lm   = lane & 15;
    const int swz  = lm & 7;
    const int ntB  = w * 4;             // output half: features ntB*16..+63
    const int rowBase = blockIdx.x * RPB;

    // ---- CC tables (validated r4 formula) ----
    if (tid < KQ) {
        const int j = tid;
        const float pi50 = 0.06283185307179586f;
        sSteps[j] = __cosf((float)j * pi50);
        float s = 0.0f;
        for (int i = 0; i <= 50; i += 2) {
            float Wi = (i == 0) ? 1.0f : 2.0f / (1.0f - (float)(i * i));
            float lam;
            if (j == 0) lam = 0.5f;
            else {
                int mp = (i * j) % 100;
                lam = __cosf((float)mp * pi50);
                if (j == 50) lam *= 0.5f;
            }
            s += (lam * 0.04f) * Wi;
        }
        sCcw[j] = s;
    }
    // ---- fp32 bias tables ----
    if (tid < HD) {
        b2f[tid] = b2[tid];
        b3f[tid] = b3[tid];
    }
    // ---- xmax scan (x: 64 KB, cache-resident) ----
    {
        const f32x4* x4 = (const f32x4*)x;
        float mx = -1e30f;
        for (int i = tid; i < B_N / 4; i += BLK) {
            f32x4 v = x4[i];
            mx = fmaxf(fmaxf(mx, fmaxf(v[0], v[1])), fmaxf(v[2], v[3]));
        }
        #pragma unroll
        for (int d = 32; d > 0; d >>= 1) mx = fmaxf(mx, __shfl_xor(mx, d));
        if (lane == 0) red2[w] = mx;
    }
    // ---- stage h^T for this block's 16 rows; init xL ----
    for (int i = tid; i < RPB * 63; i += BLK) {
        int r = i / 63, d = i - r * 63;
        hshT[d * 20 + r] = h[rowBase * 63 + i];
    }
    if (tid < RPB) xL[tid] = x[rowBase + tid];
    __syncthreads();                                   // B1

    const float xmax = fmaxf(red2[0], red2[1]) + 10.0f;

    // ---- block hpart (r22 vectorized + prefetch, verbatim) ----
    {
        const int n = tid;
        float acc[RPB];
        const float b1v = b1[n];
        #pragma unroll
        for (int r = 0; r < RPB; ++r) acc[r] = b1v;

        auto doFMA = [&](float wv, int d) {
            const float* ht = hshT + d * 20;
            #pragma unroll
            for (int rc = 0; rc < RPB / 4; ++rc) {
                f32x4 hv = *(const f32x4*)(ht + rc * 4);
                acc[rc * 4 + 0] = fmaf(wv, hv[0], acc[rc * 4 + 0]);
                acc[rc * 4 + 1] = fmaf(wv, hv[1], acc[rc * 4 + 1]);
                acc[rc * 4 + 2] = fmaf(wv, hv[2], acc[rc * 4 + 2]);
                acc[rc * 4 + 3] = fmaf(wv, hv[3], acc[rc * 4 + 3]);
            }
        };

        const float* w1row = W1 + n * IND;
        f32x4 wc = *(const f32x4*)(w1row);
        f32x4 wn = *(const f32x4*)(w1row + 4);
        doFMA(wc[1], 0); doFMA(wc[2], 1); doFMA(wc[3], 2);
        int d = 3;
        #pragma unroll 1
        for (int j = 1; j < IND / 4; ++j) {
            wc = wn;
            if (j + 1 < IND / 4)
                wn = *(const f32x4*)(w1row + 4 * (j + 1));
            doFMA(wc[0], d); doFMA(wc[1], d + 1);
            doFMA(wc[2], d + 2); doFMA(wc[3], d + 3);
            d += 4;
        }
        #pragma unroll
        for (int r = 0; r < RPB; ++r) hpL[r * HD + n] = acc[r];
    }
    __syncthreads();                                   // B2 (hpL ready; hshT dead)

    // ---- wave-resident weights: W2-half + W3-half (128 AGPR total) ----
    float w1x[16];                                     // Y1 slices 2w, 2w+1
    #pragma unroll
    for (int kh = 0; kh < 2; ++kh)
        #pragma unroll
        for (int j = 0; j < 8; ++j)
            w1x[kh * 8 + j] = W1[((2 * w + kh) * 32 + q * 8 + j) * IND];

    short8 W2A[4][4], W3A[4][4];
    #pragma unroll
    for (int nt = 0; nt < 4; ++nt) {
        #pragma unroll
        for (int kk = 0; kk < 4; ++kk) {
            const float* p2 = W2 + ((ntB + nt) * 16 + lm) * HD + kk * 32 + q * 8;
            f32x4 a0 = *(const f32x4*)(p2);
            f32x4 a1 = *(const f32x4*)(p2 + 4);
            S8U u2;
            u2.u[0] = pk_bf16(a0[0], a0[1]);
            u2.u[1] = pk_bf16(a0[2], a0[3]);
            u2.u[2] = pk_bf16(a1[0], a1[1]);
            u2.u[3] = pk_bf16(a1[2], a1[3]);
            W2A[nt][kk] = u2.s8;
            const float* p3 = W3 + ((ntB + nt) * 16 + lm) * HD + kk * 32 + q * 8;
            f32x4 c0 = *(const f32x4*)(p3);
            f32x4 c1 = *(const f32x4*)(p3 + 4);
            S8U u3;
            u3.u[0] = pk_bf16(c0[0], c0[1]);
            u3.u[1] = pk_bf16(c0[2], c0[3]);
            u3.u[2] = pk_bf16(c1[0], c1[1]);
            u3.u[3] = pk_bf16(c1[2], c1[3]);
            W3A[nt][kk] = u3.s8;
        }
    }
    f32x4 W4c[4];
    #pragma unroll
    for (int nt = 0; nt < 4; ++nt)
        W4c[nt] = *(const f32x4*)(W4 + (ntB + nt) * 16 + q * 4);
    const float b4v = b4[0];

    // ---- per-lane LDS offsets (proven formulas) ----
    int rdOff[4];                                      // full-frag read (Y1/Y2)
    #pragma unroll
    for (int kk = 0; kk < 4; ++kk)
        rdOff[kk] = lm * 256 + (((kk * 4 + q) ^ swz) << 4);
    int bld[2];                                        // this wave's Y1 slots
    #pragma unroll
    for (int kh = 0; kh < 2; ++kh)
        bld[kh] = lm * 256 + ((((2 * w + kh) * 4 + q) ^ swz) << 4);
    int wrOff[4];                                      // this wave's Y2 rows
    #pragma unroll
    for (int nt = 0; nt < 4; ++nt)
        wrOff[nt] = lm * 256 + (((2 * (ntB + nt) + (q >> 1)) ^ swz) << 4)
                  + ((q & 1) << 3);
    const int bI = ntB * 64 + q * 16;                  // bias byte off (+nt*64)
    const char* b2c = (const char*)b2f;
    const char* b3c = (const char*)b3f;
    float* vsW = poolF + w * (TPB * 32);               // per-wave vs half

    // Y1 builder: this wave contributes slices kk = 2w, 2w+1
    auto buildY1 = [&](int ib, char* dst) {
        const int s   = ib * 16 + lm;                  // <= 815 (guarded)
        const unsigned row = (unsigned)s / KQ;         // 0..15
        const int k   = s - (int)row * KQ;
        const float x0 = xL[row];
        const float X  = fmaf((xmax - x0) * 0.5f, sSteps[k] + 1.0f, x0);
        #pragma unroll
        for (int kh = 0; kh < 2; ++kh) {
            const int kk = 2 * w + kh;
            const float* hp = hpL + row * HD + kk * 32 + q * 8;
            f32x4 ha = *(const f32x4*)hp;
            f32x4 hb = *(const f32x4*)(hp + 4);
            S8U u;
            u.u[0] = pk_bf16(fmaxf(fmaf(X, w1x[kh*8+0], ha[0]), 0.f),
                             fmaxf(fmaf(X, w1x[kh*8+1], ha[1]), 0.f));
            u.u[1] = pk_bf16(fmaxf(fmaf(X, w1x[kh*8+2], ha[2]), 0.f),
                             fmaxf(fmaf(X, w1x[kh*8+3], ha[3]), 0.f));
            u.u[2] = pk_bf16(fmaxf(fmaf(X, w1x[kh*8+4], hb[0]), 0.f),
                             fmaxf(fmaf(X, w1x[kh*8+5], hb[1]), 0.f));
            u.u[3] = pk_bf16(fmaxf(fmaf(X, w1x[kh*8+6], hb[2]), 0.f),
                             fmaxf(fmaf(X, w1x[kh*8+7], hb[3]), 0.f));
            *(short8*)(dst + bld[kh]) = u.s8;
        }
    };

    // prologue: both waves build their slices of tile 0
    buildY1(0, y1x[0]);
    __syncthreads();                                   // Y1(0) ready

    // ---- phase 0: L2(0) only ----
    {
        short8 Y1f[4];
        #pragma unroll
        for (int kk = 0; kk < 4; ++kk)
            Y1f[kk] = *(const short8*)(y1x[0] + rdOff[kk]);
        buildY1(1, y1x[1]);
        f32x4 C[4];
        #pragma unroll
        for (int nt = 0; nt < 4; ++nt)
            C[nt] = *(const f32x4*)(b2c + nt * 64 + bI);
        #pragma unroll
        for (int kk = 0; kk < 4; ++kk)
            #pragma unroll
            for (int nt = 0; nt < 4; ++nt)
                C[nt] = __builtin_amdgcn_mfma_f32_16x16x32_bf16(W2A[nt][kk], Y1f[kk], C[nt], 0, 0, 0);
        #pragma unroll
        for (int nt = 0; nt < 4; ++nt) {
            unsigned lo = pk_bf16(fmaxf(C[nt][0], 0.f), fmaxf(C[nt][1], 0.f));
            unsigned hi = pk_bf16(fmaxf(C[nt][2], 0.f), fmaxf(C[nt][3], 0.f));
            *(int2*)(y2x[0] + wrOff[nt]) = make_int2((int)lo, (int)hi);
        }
        __syncthreads();                               // Y2(0), Y1(1) ready
    }

    // ---- steady loop: L3(t-1) + L2(t) per phase, both waves ----
    #pragma unroll 1
    for (int t = 1; t < TPB; ++t) {
        const char* s1 = y1x[t & 1];
        const char* s2 = y2x[(t - 1) & 1];
        short8 Y1f[4], Y2f[4];
        #pragma unroll
        for (int kk = 0; kk < 4; ++kk)
            Y2f[kk] = *(const short8*)(s2 + rdOff[kk]);
        #pragma unroll
        for (int kk = 0; kk < 4; ++kk)
            Y1f[kk] = *(const short8*)(s1 + rdOff[kk]);

        // L3(t-1) on this wave's W3-half
        f32x4 C[4];
        #pragma unroll
        for (int nt = 0; nt < 4; ++nt)
            C[nt] = *(const f32x4*)(b3c + nt * 64 + bI);
        #pragma unroll
        for (int kk = 0; kk < 4; ++kk)
            #pragma unroll
            for (int nt = 0; nt < 4; ++nt)
                C[nt] = __builtin_amdgcn_mfma_f32_16x16x32_bf16(W3A[nt][kk], Y2f[kk], C[nt], 0, 0, 0);
        float p = 0.f;
        #pragma unroll
        for (int nt = 0; nt < 4; ++nt) {
            p = fmaf(fmaxf(C[nt][0], 0.f), W4c[nt][0], p);
            p = fmaf(fmaxf(C[nt][1], 0.f), W4c[nt][1], p);
            p = fmaf(fmaxf(C[nt][2], 0.f), W4c[nt][2], p);
            p = fmaf(fmaxf(C[nt][3], 0.f), W4c[nt][3], p);
        }
        p += __shfl_xor(p, 32);
        if (lane < 32) vsW[(t - 1) * 32 + lane] = p;

        // independent VALU: next tile's Y1 slices
        if (t + 1 < TPB) buildY1(t + 1, y1x[(t + 1) & 1]);

        // L2(t) on this wave's W2-half
        f32x4 D[4];
        #pragma unroll
        for (int nt = 0; nt < 4; ++nt)
            D[nt] = *(const f32x4*)(b2c + nt * 64 + bI);
        #pragma unroll
        for (int kk = 0; kk < 4; ++kk)
            #pragma unroll
            for (int nt = 0; nt < 4; ++nt)
                D[nt] = __builtin_amdgcn_mfma_f32_16x16x32_bf16(W2A[nt][kk], Y1f[kk], D[nt], 0, 0, 0);
        char* d2 = y2x[t & 1];
        #pragma unroll
        for (int nt = 0; nt < 4; ++nt) {
            unsigned lo = pk_bf16(fmaxf(D[nt][0], 0.f), fmaxf(D[nt][1], 0.f));
            unsigned hi = pk_bf16(fmaxf(D[nt][2], 0.f), fmaxf(D[nt][3], 0.f));
            *(int2*)(d2 + wrOff[nt]) = make_int2((int)lo, (int)hi);
        }
        __syncthreads();                               // Y2(t), Y1(t+1) ready
    }

    // ---- tail: L3(TPB-1) ----
    {
        const char* s2 = y2x[(TPB - 1) & 1];
        short8 Y2f[4];
        #pragma unroll
        for (int kk = 0; kk < 4; ++kk)
            Y2f[kk] = *(const short8*)(s2 + rdOff[kk]);
        f32x4 C[4];
        #pragma unroll
        for (int nt = 0; nt < 4; ++nt)
            C[nt] = *(const f32x4*)(b3c + nt * 64 + bI);
        #pragma unroll
        for (int kk = 0; kk < 4; ++kk)
            #pragma unroll
            for (int nt = 0; nt < 4; ++nt)
                C[nt] = __builtin_amdgcn_mfma_f32_16x16x32_bf16(W3A[nt][kk], Y2f[kk], C[nt], 0, 0, 0);
        float p = 0.f;
        #pragma unroll
        for (int nt = 0; nt < 4; ++nt) {
            p = fmaf(fmaxf(C[nt][0], 0.f), W4c[nt][0], p);
            p = fmaf(fmaxf(C[nt][1], 0.f), W4c[nt][1], p);
            p = fmaf(fmaxf(C[nt][2], 0.f), W4c[nt][2], p);
            p = fmaf(fmaxf(C[nt][3], 0.f), W4c[nt][3], p);
        }
        p += __shfl_xor(p, 32);
        if (lane < 32) vsW[(TPB - 1) * 32 + lane] = p;
        __syncthreads();                               // both halves visible
    }

    // ---- deferred epilogue (wave 0): sum halves + elu + ccw + reduce ----
    if (w == 0) {
        const float* v0 = poolF;
        const float* v1 = poolF + TPB * 32;
        const int r   = lane >> 2;                     // row 0..15
        const int sub = lane & 3;
        float a = 0.f;
        #pragma unroll 1
        for (int j = 0; j < 13; ++j) {
            int k = sub + 4 * j;
            if (k < KQ) {
                int s   = r * KQ + k;
                int tt  = s >> 4;
                int lm2 = s & 15;
                float y4 = v0[tt * 32 + lm2] + v0[tt * 32 + 16 + lm2]
                         + v1[tt * 32 + lm2] + v1[tt * 32 + 16 + lm2] + b4v;
                float f  = (y4 > 0.f) ? (y4 + 1.f) : __expf(y4);
                a = fmaf(f, sCcw[k], a);
            }
        }
        a += __shfl_xor(a, 1);
        a += __shfl_xor(a, 2);
        if (sub == 0)
            out[rowBase + r] = a * (xmax - xL[r]) * 0.5f;
    }
}

// ---------------------------------------------------------------------------
extern "C" void kernel_launch(void* const* d_in, const int* in_sizes, int n_in,
                              void* d_out, int out_size, void* d_ws, size_t ws_size,
                              hipStream_t stream)
{
    const float* x  = (const float*)d_in[0];
    const float* h  = (const float*)d_in[1];
    const float* W1 = (const float*)d_in[2];
    const float* b1 = (const float*)d_in[3];
    const float* W2 = (const float*)d_in[4];
    const float* b2 = (const float*)d_in[5];
    const float* W3 = (const float*)d_in[6];
    const float* b3 = (const float*)d_in[7];
    const float* W4 = (const float*)d_in[8];
    const float* b4 = (const float*)d_in[9];
    float* out = (float*)d_out;

    umnn_fused<<<GRID, BLK, 0, stream>>>(x, h, W1, b1, W2, b2, W3, b3,
                                         W4, b4, out);
}

// Round 19
// 160.625 us; speedup vs baseline: 1.0496x; 1.0496x over previous
//
#include <hip/hip_runtime.h>
#include <hip/hip_bf16.h>
#include <math.h>

// ---------------------------------------------------------------------------
// Round 26 (FINAL): exact revert to r22/r24 -- the session's measured best,
// now reproduced twice (rocprof 104-110us, bench 162.3/162.6us, absmax
// 0.125; inherited baseline was 186.4us bench / 132us rocprof).
// Architecture: 2-wave producer/consumer, per-tile barrier, bf16 Y2
// handoff; vectorized+prefetched prologue load paths (the r22 win: -17us
// from removing the 63-deep dependent scalar W1 load chain in hpart and
// scalar W2/W3 fragment staging).
// CLOSED design matrix -- 14 loop-structure variants, all measured worse:
//   sync topology: pair-barriers 119, flag-ring 125
//   4-wave split-weights: 144 / spill / numerics-fail
//   symmetric layer-split (W2half+W3half per wave): 120-122, bank
//     conflicts 3.3M->5.8M from Y1 round-trip (r25)
//   L1-on-MFMA: 122; consumer span cuts: 120; pk_fma: 118
//   X software pipeline + w1col: 109-112 (X-prep already hidden)
//   asm-pinned AGPR MFMA: hazard corruption (absmax 4.9)
// Limit: latency-bound at register-capped 2 waves/SIMD -- 128-AGPR weight
// residency is irreducible (half-weight schemes still hold 128 and add an
// LDS round-trip; LDS weight streaming exceeds LDS BW; fp8 weights exceed
// the 0.4725 error budget). Not a HW roofline (MfmaUtil ~21%, HBM 0.4%);
// a structure-local minimum with every escape path measured negative.
// Session noise floor ~5us cross-session, ~2us within-session.
// ---------------------------------------------------------------------------

#define B_N    16384
#define KQ     51
#define HD     128
#define IND    64
#define BLK    128               // 2 waves: producer + consumer
#define RPB    16                // b-rows per block
#define GRID   (B_N / RPB)       // 1024
#define TPB    ((RPB * KQ) / 16) // 51 tiles per block (exact)

typedef __attribute__((ext_vector_type(8))) short short8;
typedef __attribute__((ext_vector_type(4))) float f32x4;

union S8U { short8 s8; unsigned u[4]; };

__device__ __forceinline__ unsigned short f2bf(float f) {
    __hip_bfloat16 t = __float2bfloat16(f);
    return *reinterpret_cast<unsigned short*>(&t);
}

#if defined(__gfx950__) && defined(__has_builtin)
#if __has_builtin(__builtin_amdgcn_cvt_pk_bf16_f32)
#define HAVE_PK_BF16 1
#endif
#endif

__device__ __forceinline__ unsigned pk_bf16(float lo, float hi) {
#ifdef HAVE_PK_BF16
    typedef __attribute__((ext_vector_type(2))) __bf16 bfv2;
    bfv2 r = __builtin_amdgcn_cvt_pk_bf16_f32(lo, hi);
    return *reinterpret_cast<unsigned*>(&r);
#else
    return (unsigned)f2bf(lo) | ((unsigned)f2bf(hi) << 16);
#endif
}

__launch_bounds__(BLK, 2)
__global__ void umnn_fused(const float* __restrict__ x,  const float* __restrict__ h,
                           const float* __restrict__ W1, const float* __restrict__ b1,
                           const float* __restrict__ W2, const float* __restrict__ b2,
                           const float* __restrict__ W3, const float* __restrict__ b3,
                           const float* __restrict__ W4, const float* __restrict__ b4,
                           float* __restrict__ out)
{
    __shared__ __align__(16) float hpL[RPB * HD];      // 8 KB block hpart
    __shared__ __align__(16) char  y2x[2][4096];       // 8 KB Y2 double buffer
    __shared__ __align__(16) float hshT[63 * 20];      // 5 KB h^T staging
    __shared__ __align__(16) float vs4[TPB * 64];      // 12.75 KB per-lane partials
    __shared__ __align__(16) float b2f[HD], b3f[HD];   // 1 KB fp32 bias tables
    __shared__ float xL[RPB];
    __shared__ float sSteps[KQ], sCcw[KQ];
    __shared__ float red2[2];

    const int tid  = threadIdx.x;
    const int w    = tid >> 6;
    const int lane = tid & 63;
    const int q    = lane >> 4;
    const int lm   = lane & 15;
    const int swz  = lm & 7;
    const int rowBase = blockIdx.x * RPB;

    // ---- CC tables (validated r4 formula) ----
    if (tid < KQ) {
        const int j = tid;
        const float pi50 = 0.06283185307179586f;
        sSteps[j] = __cosf((float)j * pi50);
        float s = 0.0f;
        for (int i = 0; i <= 50; i += 2) {
            float Wi = (i == 0) ? 1.0f : 2.0f / (1.0f - (float)(i * i));
            float lam;
            if (j == 0) lam = 0.5f;
            else {
                int mp = (i * j) % 100;
                lam = __cosf((float)mp * pi50);
                if (j == 50) lam *= 0.5f;
            }
            s += (lam * 0.04f) * Wi;
        }
        sCcw[j] = s;
    }
    // ---- fp32 bias tables ----
    if (tid < HD) {
        b2f[tid] = b2[tid];
        b3f[tid] = b3[tid];
    }
    // ---- xmax scan (x: 64 KB, cache-resident) ----
    {
        const f32x4* x4 = (const f32x4*)x;
        float mx = -1e30f;
        for (int i = tid; i < B_N / 4; i += BLK) {
            f32x4 v = x4[i];
            mx = fmaxf(fmaxf(mx, fmaxf(v[0], v[1])), fmaxf(v[2], v[3]));
        }
        #pragma unroll
        for (int d = 32; d > 0; d >>= 1) mx = fmaxf(mx, __shfl_xor(mx, d));
        if (lane == 0) red2[w] = mx;
    }
    // ---- stage h^T for this block's 16 rows; init xL ----
    for (int i = tid; i < RPB * 63; i += BLK) {
        int r = i / 63, d = i - r * 63;
        hshT[d * 20 + r] = h[rowBase * 63 + i];
    }
    if (tid < RPB) xL[tid] = x[rowBase + tid];
    __syncthreads();                                   // B1

    const float xmax = fmaxf(red2[0], red2[1]) + 10.0f;

    // ---- block hpart: thread tid = feature n, 16 row-accumulators.
    //      W1 row loaded as 16 aligned f32x4 chunks with 1-chunk prefetch
    //      (was 63 dependent scalar loads). Accum order d=0..62 unchanged.
    {
        const int n = tid;
        float acc[RPB];
        const float b1v = b1[n];
        #pragma unroll
        for (int r = 0; r < RPB; ++r) acc[r] = b1v;

        auto doFMA = [&](float wv, int d) {
            const float* ht = hshT + d * 20;
            #pragma unroll
            for (int rc = 0; rc < RPB / 4; ++rc) {
                f32x4 hv = *(const f32x4*)(ht + rc * 4);
                acc[rc * 4 + 0] = fmaf(wv, hv[0], acc[rc * 4 + 0]);
                acc[rc * 4 + 1] = fmaf(wv, hv[1], acc[rc * 4 + 1]);
                acc[rc * 4 + 2] = fmaf(wv, hv[2], acc[rc * 4 + 2]);
                acc[rc * 4 + 3] = fmaf(wv, hv[3], acc[rc * 4 + 3]);
            }
        };

        const float* w1row = W1 + n * IND;             // 16B-aligned row base
        f32x4 wc = *(const f32x4*)(w1row);             // cols 0..3 (col 0 = x-col, unused)
        f32x4 wn = *(const f32x4*)(w1row + 4);
        doFMA(wc[1], 0); doFMA(wc[2], 1); doFMA(wc[3], 2);
        int d = 3;
        #pragma unroll 1
        for (int j = 1; j < IND / 4; ++j) {            // chunks 1..15
            wc = wn;
            if (j + 1 < IND / 4)
                wn = *(const f32x4*)(w1row + 4 * (j + 1));  // prefetch next
            doFMA(wc[0], d); doFMA(wc[1], d + 1);
            doFMA(wc[2], d + 2); doFMA(wc[3], d + 3);
            d += 4;
        }
        #pragma unroll
        for (int r = 0; r < RPB; ++r) hpL[r * HD + n] = acc[r];
    }
    __syncthreads();                                   // B2 (hpL ready)

    // per-lane C-init byte offset into bias table: feature nt*16+q*4
    const int bIoff = q * 16;                          // + nt*64 at use site

    if (w == 0) {
        // ================= PRODUCER: layer 1 + layer 2 =================
        __builtin_amdgcn_s_setprio(0);
        float w1x[32];
        #pragma unroll
        for (int kk = 0; kk < 4; ++kk)
            #pragma unroll
            for (int j = 0; j < 8; ++j)
                w1x[kk * 8 + j] = W1[(kk * 32 + q * 8 + j) * IND];

        short8 W2A[8][4];
        #pragma unroll
        for (int nt = 0; nt < 8; ++nt) {
            #pragma unroll
            for (int kk = 0; kk < 4; ++kk) {
                const float* p2 = W2 + (nt * 16 + lm) * HD + kk * 32 + q * 8;
                f32x4 v0 = *(const f32x4*)(p2);        // aligned (32B offset)
                f32x4 v1 = *(const f32x4*)(p2 + 4);
                S8U a2;
                a2.u[0] = pk_bf16(v0[0], v0[1]);
                a2.u[1] = pk_bf16(v0[2], v0[3]);
                a2.u[2] = pk_bf16(v1[0], v1[1]);
                a2.u[3] = pk_bf16(v1[2], v1[3]);
                W2A[nt][kk] = a2.s8;
            }
        }
        int wrOff[8];
        #pragma unroll
        for (int nt = 0; nt < 8; ++nt)
            wrOff[nt] = lm * 256 + (((2 * nt + (q >> 1)) ^ swz) << 4) + ((q & 1) << 3);
        const char* b2c = (const char*)b2f;

        #pragma unroll 1
        for (int tt = 0; tt < TPB; ++tt) {
            // ---- layer 1: build Y1 fragment for this tile ----
            const int s    = tt * 16 + lm;             // 0..815
            const unsigned row = (unsigned)s / KQ;     // 0..15
            const int k    = s - (int)row * KQ;
            const float x0 = xL[row];
            const float X  = fmaf((xmax - x0) * 0.5f, sSteps[k] + 1.0f, x0);
            short8 Y1[4];
            #pragma unroll
            for (int kk = 0; kk < 4; ++kk) {
                const float* hp = hpL + row * HD + kk * 32 + q * 8;
                f32x4 ha = *(const f32x4*)hp;
                f32x4 hb = *(const f32x4*)(hp + 4);
                S8U u;
                u.u[0] = pk_bf16(fmaxf(fmaf(X, w1x[kk*8+0], ha[0]), 0.f),
                                 fmaxf(fmaf(X, w1x[kk*8+1], ha[1]), 0.f));
                u.u[1] = pk_bf16(fmaxf(fmaf(X, w1x[kk*8+2], ha[2]), 0.f),
                                 fmaxf(fmaf(X, w1x[kk*8+3], ha[3]), 0.f));
                u.u[2] = pk_bf16(fmaxf(fmaf(X, w1x[kk*8+4], hb[0]), 0.f),
                                 fmaxf(fmaf(X, w1x[kk*8+5], hb[1]), 0.f));
                u.u[3] = pk_bf16(fmaxf(fmaf(X, w1x[kk*8+6], hb[2]), 0.f),
                                 fmaxf(fmaf(X, w1x[kk*8+7], hb[3]), 0.f));
                Y1[kk] = u.s8;
            }

            // ---- layer 2: C init from LDS bias table, 32 MFMA ----
            f32x4 C[8];
            #pragma unroll
            for (int nt = 0; nt < 8; ++nt)
                C[nt] = *(const f32x4*)(b2c + nt * 64 + bIoff);
            #pragma unroll
            for (int kk = 0; kk < 4; ++kk)
                #pragma unroll
                for (int nt = 0; nt < 8; ++nt)
                    C[nt] = __builtin_amdgcn_mfma_f32_16x16x32_bf16(W2A[nt][kk], Y1[kk], C[nt], 0, 0, 0);

            // ---- relu + pack + write Y2 ----
            char* d2 = y2x[tt & 1];
            #pragma unroll
            for (int nt = 0; nt < 8; ++nt) {
                unsigned lo = pk_bf16(fmaxf(C[nt][0], 0.f), fmaxf(C[nt][1], 0.f));
                unsigned hi = pk_bf16(fmaxf(C[nt][2], 0.f), fmaxf(C[nt][3], 0.f));
                *(int2*)(d2 + wrOff[nt]) = make_int2((int)lo, (int)hi);
            }
            __syncthreads();                           // tile tt ready
        }
    } else {
        // ================= CONSUMER: layer 3 + layer 4 =================
        __builtin_amdgcn_s_setprio(1);                 // consumer is critical
        short8 W3A[8][4];
        f32x4  W4c[8];
        #pragma unroll
        for (int nt = 0; nt < 8; ++nt) {
            #pragma unroll
            for (int kk = 0; kk < 4; ++kk) {
                const float* p3 = W3 + (nt * 16 + lm) * HD + kk * 32 + q * 8;
                f32x4 v0 = *(const f32x4*)(p3);        // aligned (32B offset)
                f32x4 v1 = *(const f32x4*)(p3 + 4);
                S8U a3;
                a3.u[0] = pk_bf16(v0[0], v0[1]);
                a3.u[1] = pk_bf16(v0[2], v0[3]);
                a3.u[2] = pk_bf16(v1[0], v1[1]);
                a3.u[3] = pk_bf16(v1[2], v1[3]);
                W3A[nt][kk] = a3.s8;
            }
            W4c[nt] = *(const f32x4*)(W4 + nt * 16 + q * 4);
        }
        const float b4v = b4[0];
        int rdOff[4];
        #pragma unroll
        for (int kk = 0; kk < 4; ++kk)
            rdOff[kk] = lm * 256 + (((kk * 4 + q) ^ swz) << 4);
        const char* b3c = (const char*)b3f;

        #pragma unroll 1
        for (int tt = 0; tt < TPB; ++tt) {
            __syncthreads();                           // wait for tile tt
            const char* s2 = y2x[tt & 1];

            // chain head: Y2 reads + C-init reads, all pipelined LDS
            short8 Y2[4];
            #pragma unroll
            for (int kk = 0; kk < 4; ++kk)
                Y2[kk] = *(const short8*)(s2 + rdOff[kk]);
            f32x4 C[8];
            #pragma unroll
            for (int nt = 0; nt < 8; ++nt)
                C[nt] = *(const f32x4*)(b3c + nt * 64 + bIoff);

            #pragma unroll
            for (int kk = 0; kk < 4; ++kk)
                #pragma unroll
                for (int nt = 0; nt < 8; ++nt)
                    C[nt] = __builtin_amdgcn_mfma_f32_16x16x32_bf16(W3A[nt][kk], Y2[kk], C[nt], 0, 0, 0);

            // ---- layer 4 per-lane partial: NO shuffles, straight to LDS ----
            float p = 0.f;
            #pragma unroll
            for (int nt = 0; nt < 8; ++nt) {
                p = fmaf(fmaxf(C[nt][0], 0.f), W4c[nt][0], p);
                p = fmaf(fmaxf(C[nt][1], 0.f), W4c[nt][1], p);
                p = fmaf(fmaxf(C[nt][2], 0.f), W4c[nt][2], p);
                p = fmaf(fmaxf(C[nt][3], 0.f), W4c[nt][3], p);
            }
            vs4[tt * 64 + lane] = p;                   // conflict-free
        }

        // ---- deferred epilogue: 4-way quarter sum + elu + ccw + reduce ----
        {
            const int r   = lane >> 2;                 // row 0..15
            const int sub = lane & 3;
            float a = 0.f;
            #pragma unroll 1
            for (int j = 0; j < 13; ++j) {
                int k = sub + 4 * j;
                if (k < KQ) {
                    int s   = r * KQ + k;
                    int tt  = s >> 4;
                    int lm2 = s & 15;
                    const float* vb = vs4 + tt * 64 + lm2;
                    float y4 = vb[0] + vb[16] + vb[32] + vb[48] + b4v;
                    float f  = (y4 > 0.f) ? (y4 + 1.f) : __expf(y4);
                    a = fmaf(f, sCcw[k], a);
                }
            }
            a += __shfl_xor(a, 1);
            a += __shfl_xor(a, 2);
            if (sub == 0)
                out[rowBase + r] = a * (xmax - xL[r]) * 0.5f;
        }
    }
}

// ---------------------------------------------------------------------------
extern "C" void kernel_launch(void* const* d_in, const int* in_sizes, int n_in,
                              void* d_out, int out_size, void* d_ws, size_t ws_size,
                              hipStream_t stream)
{
    const float* x  = (const float*)d_in[0];
    const float* h  = (const float*)d_in[1];
    const float* W1 = (const float*)d_in[2];
    const float* b1 = (const float*)d_in[3];
    const float* W2 = (const float*)d_in[4];
    const float* b2 = (const float*)d_in[5];
    const float* W3 = (const float*)d_in[6];
    const float* b3 = (const float*)d_in[7];
    const float* W4 = (const float*)d_in[8];
    const float* b4 = (const float*)d_in[9];
    float* out = (float*)d_out;

    umnn_fused<<<GRID, BLK, 0, stream>>>(x, h, W1, b1, W2, b2, W3, b3,
                                         W4, b4, out);
}